// Round 11
// baseline (123.735 us; speedup 1.0000x reference)
//
#include <hip/hip_runtime.h>

#define NDOF 7
#define BLK 256
#define CST_STRIDE 24               // floats per dof block (= 6 float4)
#define CST_TOT (NDOF * CST_STRIDE) // 168
#define FREC 43                     // per-thread fl/fa record stride (43 mod 32 = 11, coprime -> conflict-free)

// ---------- tiny vec3 ----------
struct V3 { float x, y, z; };
__device__ __forceinline__ V3 operator+(V3 a, V3 b) { return {a.x + b.x, a.y + b.y, a.z + b.z}; }
__device__ __forceinline__ V3 operator-(V3 a, V3 b) { return {a.x - b.x, a.y - b.y, a.z - b.z}; }
__device__ __forceinline__ V3 operator*(float s, V3 a) { return {s * a.x, s * a.y, s * a.z}; }
__device__ __forceinline__ V3 cross(V3 a, V3 b) {
    return {a.y * b.z - a.z * b.y, a.z * b.x - a.x * b.z, a.x * b.y - a.y * b.x};
}
__device__ __forceinline__ float dot(V3 a, V3 b) { return a.x * b.x + a.y * b.y + a.z * b.z; }

// ---------- prep: pack per-dof constants into d_ws ----------
// per dof d (24 floats): [0:3)Fc0 [3:6)Fc1 [6:9)Fc2 [9:12)p
// [12:18) Io6=I00,I01,I02,I11,I12,I22  [18]m [19:22)mc [22]damp [23]pad
__global__ void rnea_prep(const float* __restrict__ rot_fix,
                          const float* __restrict__ trans_fix,
                          const float* __restrict__ mass_g,
                          const float* __restrict__ com_g,
                          const float* __restrict__ inertia_g,
                          const float* __restrict__ damping_g,
                          float* __restrict__ cst) {
    const int d = threadIdx.x;
    if (d >= NDOF) return;
    float* o = cst + d * CST_STRIDE;
    const float* F = rot_fix + (1 + d) * 9;
#pragma unroll
    for (int j = 0; j < 3; j++)
#pragma unroll
        for (int i = 0; i < 3; i++) o[j * 3 + i] = F[i * 3 + j];  // column-major
#pragma unroll
    for (int i = 0; i < 3; i++) o[9 + i] = trans_fix[(1 + d) * 3 + i];
    const float m = mass_g[1 + d];
    const float c0 = com_g[(1 + d) * 3 + 0];
    const float c1 = com_g[(1 + d) * 3 + 1];
    const float c2 = com_g[(1 + d) * 3 + 2];
    const float* I = inertia_g + (1 + d) * 9;
    o[12] = I[0] + m * (c1 * c1 + c2 * c2);
    o[13] = I[1] - m * c0 * c1;
    o[14] = I[2] - m * c0 * c2;
    o[15] = I[4] + m * (c0 * c0 + c2 * c2);
    o[16] = I[5] - m * c1 * c2;
    o[17] = I[8] + m * (c0 * c0 + c1 * c1);
    o[18] = m;
    o[19] = m * c0;
    o[20] = m * c1;
    o[21] = m * c2;
    o[22] = damping_g[d];
    o[23] = 0.f;
}

// AX: 0 = +z, 1 = +y, 2 = -y   (joint_axes is a literal in the reference)
template <int AX>
__device__ __forceinline__ void make_R(V3 Fc0, V3 Fc1, V3 Fc2, float s, float c,
                                       V3& R0, V3& R1, V3& R2) {
    if (AX == 0) {          // Rq_z cols: (c,s,0), (-s,c,0), (0,0,1)
        R0 = c * Fc0 + s * Fc1;
        R1 = c * Fc1 - s * Fc0;
        R2 = Fc2;
    } else if (AX == 1) {   // Rq_y cols: (c,0,-s), (0,1,0), (s,0,c)
        R0 = c * Fc0 - s * Fc2;
        R1 = Fc1;
        R2 = s * Fc0 + c * Fc2;
    } else {                // Rq_-y cols: (c,0,s), (0,1,0), (-s,0,c)
        R0 = c * Fc0 + s * Fc2;
        R1 = Fc1;
        R2 = c * Fc2 - s * Fc0;
    }
}

// fwd: parks fl/fa (6 floats) in the thread's LDS record at link d.
// NON-volatile + a __syncthreads() between passes = LDS clobber, so the
// compiler cannot promote sF back to registers (r8) yet accesses stay
// batchable (r9's volatile serialized every access and regressed).
// Constants staged per-step as 6x ds_read_b128 (r10 re-read ~21 scattered
// b32 per step at VGPR 72 -> ~3400 inst/thread).
template <int AX>
__device__ __forceinline__ void fwd_step(const float4* C4, float* frec, float s, float c,
                                         float qd, float qdd, V3& vl, V3& va, V3& al,
                                         V3& aa) {
    const float4 A0 = C4[0], A1 = C4[1], A2 = C4[2], A3 = C4[3], A4 = C4[4], A5 = C4[5];
    const V3 Fc0{A0.x, A0.y, A0.z};
    const V3 Fc1{A0.w, A1.x, A1.y};
    const V3 Fc2{A1.z, A1.w, A2.x};
    const V3 p{A2.y, A2.z, A2.w};
    const float I00 = A3.x, I01 = A3.y, I02 = A3.z, I11 = A3.w, I12 = A4.x, I22 = A4.y;
    const float m = A4.z;
    const V3 mc{A4.w, A5.x, A5.y};

    V3 R0, R1, R2;
    make_R<AX>(Fc0, Fc1, Fc2, s, c, R0, R1, R2);

    // Rt(vl) + cross(-Rt p, Rt va) == Rt(vl + va x p)
    V3 w1 = vl + cross(va, p);
    V3 w2 = al + cross(aa, p);
    V3 nvl{dot(R0, w1), dot(R1, w1), dot(R2, w1)};
    V3 nva{dot(R0, va), dot(R1, va), dot(R2, va)};
    V3 nal{dot(R0, w2), dot(R1, w2), dot(R2, w2)};
    V3 naa{dot(R0, aa), dot(R1, aa), dot(R2, aa)};

    if (AX == 0) {          // jv=(0,0,qd): cross(v,jv)=(v.y*qd,-v.x*qd,0)
        va = {nva.x, nva.y, nva.z + qd};
        aa = {naa.x + va.y * qd, naa.y - va.x * qd, naa.z + qdd};
        vl = nvl;
        al = {nal.x + vl.y * qd, nal.y - vl.x * qd, nal.z};
    } else if (AX == 1) {   // jv=(0,qd,0): cross(v,jv)=(-v.z*qd,0,v.x*qd)
        va = {nva.x, nva.y + qd, nva.z};
        aa = {naa.x - va.z * qd, naa.y + qdd, naa.z + va.x * qd};
        vl = nvl;
        al = {nal.x - vl.z * qd, nal.y, nal.z + vl.x * qd};
    } else {                // jv=(0,-qd,0): cross(v,jv)=(v.z*qd,0,-v.x*qd)
        va = {nva.x, nva.y - qd, nva.z};
        aa = {naa.x + va.z * qd, naa.y - qdd, naa.z - va.x * qd};
        vl = nvl;
        al = {nal.x + vl.z * qd, nal.y, nal.z - vl.x * qd};
    }

    V3 Ial = m * al + cross(aa, mc);
    V3 Iaa = V3{I00 * aa.x + I01 * aa.y + I02 * aa.z,
                I01 * aa.x + I11 * aa.y + I12 * aa.z,
                I02 * aa.x + I12 * aa.y + I22 * aa.z} + cross(mc, al);
    V3 Ivl = m * vl + cross(va, mc);
    V3 Iva = V3{I00 * va.x + I01 * va.y + I02 * va.z,
                I01 * va.x + I11 * va.y + I12 * va.z,
                I02 * va.x + I12 * va.y + I22 * va.z} + cross(mc, vl);
    V3 fl = Ial + cross(va, Ivl);
    V3 fa = Iaa + cross(va, Iva) + cross(vl, Ivl);
    frec[0] = fl.x; frec[1] = fl.y; frec[2] = fl.z;
    frec[3] = fa.x; frec[4] = fa.y; frec[5] = fa.z;
}

template <int AX>
__device__ __forceinline__ float bwd_step(const float4* C4, const float* frec,
                                          float s, float c, V3& cl, V3& ca) {
    const float4 A0 = C4[0], A1 = C4[1], A2 = C4[2];   // only F and p needed
    const V3 Fc0{A0.x, A0.y, A0.z};
    const V3 Fc1{A0.w, A1.x, A1.y};
    const V3 Fc2{A1.z, A1.w, A2.x};
    const V3 p{A2.y, A2.z, A2.w};

    V3 fl{frec[0], frec[1], frec[2]};
    V3 fa{frec[3], frec[4], frec[5]};
    V3 tl = fl + cl;
    V3 ta = fa + ca;
    float tau;
    if (AX == 0) tau = ta.z;
    else if (AX == 1) tau = ta.y;
    else tau = -ta.y;

    V3 R0, R1, R2;
    make_R<AX>(Fc0, Fc1, Fc2, s, c, R0, R1, R2);
    V3 nl = tl.x * R0 + tl.y * R1 + tl.z * R2;   // R @ tl (columns)
    V3 na = ta.x * R0 + ta.y * R1 + ta.z * R2 + cross(p, nl);
    cl = nl;
    ca = na;
    return tau;
}

// ---------- main kernel ----------
// No allocator-forcing attributes: rounds 2/5/7 showed any occupancy cap on
// this kernel triggers catastrophic scratch spill. LDS caps residency at
// 3 blocks/CU (12 waves), so VGPR headroom up to ~170 is free — spent here
// on reg-carried sin/cos and float4-staged step constants.
__global__ __launch_bounds__(BLK) void rnea_main(
    const float* __restrict__ q_g, const float* __restrict__ qd_g,
    const float* __restrict__ qdd_g, const float* __restrict__ cst,
    float* __restrict__ out, int nbatch) {
    __shared__ __align__(16) float sC[CST_TOT];
    __shared__ __align__(16) float sF[BLK * FREC];   // per-thread fl/fa records, 44 KB
    const int t = threadIdx.x;
    const int row = blockIdx.x * BLK + t;

    if (t < CST_TOT) sC[t] = cst[t];
    __syncthreads();

    const bool ok = row < nbatch;
    const size_t go = (size_t)row * NDOF;
    float qd[NDOF], ss[NDOF], cc[NDOF];
    V3 vl{0.f, 0.f, 0.f}, va{0.f, 0.f, 0.f}, al{0.f, 0.f, 9.81f}, aa{0.f, 0.f, 0.f};
    float* frec = sF + t * FREC;

    if (ok) {
        float q[NDOF], qdd[NDOF];
#pragma unroll
        for (int d = 0; d < NDOF; d++) q[d] = q_g[go + d];
#pragma unroll
        for (int d = 0; d < NDOF; d++) qd[d] = qd_g[go + d];
#pragma unroll
        for (int d = 0; d < NDOF; d++) qdd[d] = qdd_g[go + d];
        // all transcendentals upfront: 7 independent pairs overlap in the
        // trans pipe and leave the recursion's dependent chain
#pragma unroll
        for (int d = 0; d < NDOF; d++) { ss[d] = __sinf(q[d]); cc[d] = __cosf(q[d]); }

        const float4* C4 = reinterpret_cast<const float4*>(sC);
        // axis sequence: z, y, z, -y, z, y, z
        fwd_step<0>(C4 + 0 * 6, frec + 0 * 6, ss[0], cc[0], qd[0], qdd[0], vl, va, al, aa);
        fwd_step<1>(C4 + 1 * 6, frec + 1 * 6, ss[1], cc[1], qd[1], qdd[1], vl, va, al, aa);
        fwd_step<0>(C4 + 2 * 6, frec + 2 * 6, ss[2], cc[2], qd[2], qdd[2], vl, va, al, aa);
        fwd_step<2>(C4 + 3 * 6, frec + 3 * 6, ss[3], cc[3], qd[3], qdd[3], vl, va, al, aa);
        fwd_step<0>(C4 + 4 * 6, frec + 4 * 6, ss[4], cc[4], qd[4], qdd[4], vl, va, al, aa);
        fwd_step<1>(C4 + 5 * 6, frec + 5 * 6, ss[5], cc[5], qd[5], qdd[5], vl, va, al, aa);
        fwd_step<0>(C4 + 6 * 6, frec + 6 * 6, ss[6], cc[6], qd[6], qdd[6], vl, va, al, aa);
    }

    // LDS fence: blocks store->load forwarding / promotion of sF — ends the
    // fl/fa register live ranges at the fwd stores (r10: VGPR 200 -> 72).
    __syncthreads();

    if (ok) {
        const float4* C4 = reinterpret_cast<const float4*>(sC);
        V3 cl{0.f, 0.f, 0.f}, ca{0.f, 0.f, 0.f};
        float tau[NDOF];
        tau[6] = bwd_step<0>(C4 + 6 * 6, frec + 6 * 6, ss[6], cc[6], cl, ca);
        tau[5] = bwd_step<1>(C4 + 5 * 6, frec + 5 * 6, ss[5], cc[5], cl, ca);
        tau[4] = bwd_step<0>(C4 + 4 * 6, frec + 4 * 6, ss[4], cc[4], cl, ca);
        tau[3] = bwd_step<2>(C4 + 3 * 6, frec + 3 * 6, ss[3], cc[3], cl, ca);
        tau[2] = bwd_step<0>(C4 + 2 * 6, frec + 2 * 6, ss[2], cc[2], cl, ca);
        tau[1] = bwd_step<1>(C4 + 1 * 6, frec + 1 * 6, ss[1], cc[1], cl, ca);
        tau[0] = bwd_step<0>(C4 + 0 * 6, frec + 0 * 6, ss[0], cc[0], cl, ca);

#pragma unroll
        for (int d = 0; d < NDOF; d++)
            out[go + d] = tau[d] + sC[d * CST_STRIDE + 22] * qd[d];
    }
}

extern "C" void kernel_launch(void* const* d_in, const int* in_sizes, int n_in,
                              void* d_out, int out_size, void* d_ws, size_t ws_size,
                              hipStream_t stream) {
    const float* q = (const float*)d_in[0];
    const float* qd = (const float*)d_in[1];
    const float* qdd = (const float*)d_in[2];
    const float* rot_fix = (const float*)d_in[3];
    const float* trans_fix = (const float*)d_in[4];
    // d_in[5] = joint_axes: compile-time constant in the reference (z,y,z,-y,z,y,z)
    const float* mass = (const float*)d_in[6];
    const float* com = (const float*)d_in[7];
    const float* inertia = (const float*)d_in[8];
    const float* damping = (const float*)d_in[9];
    float* out = (float*)d_out;
    float* cst = (float*)d_ws;  // 7*24*4 = 672 B

    const int n_elem = in_sizes[0];  // B * 7
    const int B = n_elem / NDOF;
    const int grid = (B + BLK - 1) / BLK;

    rnea_prep<<<1, 64, 0, stream>>>(rot_fix, trans_fix, mass, com, inertia, damping, cst);
    rnea_main<<<grid, BLK, 0, stream>>>(q, qd, qdd, cst, out, B);
}

// Round 12
// 122.884 us; speedup vs baseline: 1.0069x; 1.0069x over previous
//
#include <hip/hip_runtime.h>

#define NDOF 7
#define BLK 256
#define CST_STRIDE 24               // floats per dof block (= 6 float4)
#define CST_TOT (NDOF * CST_STRIDE) // 168
#define NPARK 5                     // links 0..4 parked in LDS; 5,6 fused in regs
#define FREC 33                     // 30 used +3 pad; (33L+k)%32=(L+k)%32 -> 2-way max = free

// ---------- tiny vec3 ----------
struct V3 { float x, y, z; };
__device__ __forceinline__ V3 operator+(V3 a, V3 b) { return {a.x + b.x, a.y + b.y, a.z + b.z}; }
__device__ __forceinline__ V3 operator-(V3 a, V3 b) { return {a.x - b.x, a.y - b.y, a.z - b.z}; }
__device__ __forceinline__ V3 operator*(float s, V3 a) { return {s * a.x, s * a.y, s * a.z}; }
__device__ __forceinline__ V3 cross(V3 a, V3 b) {
    return {a.y * b.z - a.z * b.y, a.z * b.x - a.x * b.z, a.x * b.y - a.y * b.x};
}
__device__ __forceinline__ float dot(V3 a, V3 b) { return a.x * b.x + a.y * b.y + a.z * b.z; }

// ---------- prep: pack per-dof constants into d_ws ----------
// per dof d (24 floats): [0:3)Fc0 [3:6)Fc1 [6:9)Fc2 [9:12)p
// [12:18) Io6=I00,I01,I02,I11,I12,I22  [18]m [19:22)mc [22]damp [23]pad
__global__ void rnea_prep(const float* __restrict__ rot_fix,
                          const float* __restrict__ trans_fix,
                          const float* __restrict__ mass_g,
                          const float* __restrict__ com_g,
                          const float* __restrict__ inertia_g,
                          const float* __restrict__ damping_g,
                          float* __restrict__ cst) {
    const int d = threadIdx.x;
    if (d >= NDOF) return;
    float* o = cst + d * CST_STRIDE;
    const float* F = rot_fix + (1 + d) * 9;
#pragma unroll
    for (int j = 0; j < 3; j++)
#pragma unroll
        for (int i = 0; i < 3; i++) o[j * 3 + i] = F[i * 3 + j];  // column-major
#pragma unroll
    for (int i = 0; i < 3; i++) o[9 + i] = trans_fix[(1 + d) * 3 + i];
    const float m = mass_g[1 + d];
    const float c0 = com_g[(1 + d) * 3 + 0];
    const float c1 = com_g[(1 + d) * 3 + 1];
    const float c2 = com_g[(1 + d) * 3 + 2];
    const float* I = inertia_g + (1 + d) * 9;
    o[12] = I[0] + m * (c1 * c1 + c2 * c2);
    o[13] = I[1] - m * c0 * c1;
    o[14] = I[2] - m * c0 * c2;
    o[15] = I[4] + m * (c0 * c0 + c2 * c2);
    o[16] = I[5] - m * c1 * c2;
    o[17] = I[8] + m * (c0 * c0 + c1 * c1);
    o[18] = m;
    o[19] = m * c0;
    o[20] = m * c1;
    o[21] = m * c2;
    o[22] = damping_g[d];
    o[23] = 0.f;
}

// AX: 0 = +z, 1 = +y, 2 = -y   (joint_axes is a literal in the reference)
template <int AX>
__device__ __forceinline__ void make_R(V3 Fc0, V3 Fc1, V3 Fc2, float s, float c,
                                       V3& R0, V3& R1, V3& R2) {
    if (AX == 0) {          // Rq_z cols: (c,s,0), (-s,c,0), (0,0,1)
        R0 = c * Fc0 + s * Fc1;
        R1 = c * Fc1 - s * Fc0;
        R2 = Fc2;
    } else if (AX == 1) {   // Rq_y cols: (c,0,-s), (0,1,0), (s,0,c)
        R0 = c * Fc0 - s * Fc2;
        R1 = Fc1;
        R2 = s * Fc0 + c * Fc2;
    } else {                // Rq_-y cols: (c,0,s), (0,1,0), (-s,0,c)
        R0 = c * Fc0 + s * Fc2;
        R1 = Fc1;
        R2 = c * Fc2 - s * Fc0;
    }
}

// fwd: computes this link's fl/fa into out-refs (caller parks 0..4 in LDS).
// Constants staged as 6x ds_read_b128 from LDS (r11).
template <int AX>
__device__ __forceinline__ void fwd_step(const float4* C4, float s, float c,
                                         float qd, float qdd, V3& vl, V3& va, V3& al,
                                         V3& aa, V3& fl, V3& fa) {
    const float4 A0 = C4[0], A1 = C4[1], A2 = C4[2], A3 = C4[3], A4 = C4[4], A5 = C4[5];
    const V3 Fc0{A0.x, A0.y, A0.z};
    const V3 Fc1{A0.w, A1.x, A1.y};
    const V3 Fc2{A1.z, A1.w, A2.x};
    const V3 p{A2.y, A2.z, A2.w};
    const float I00 = A3.x, I01 = A3.y, I02 = A3.z, I11 = A3.w, I12 = A4.x, I22 = A4.y;
    const float m = A4.z;
    const V3 mc{A4.w, A5.x, A5.y};

    V3 R0, R1, R2;
    make_R<AX>(Fc0, Fc1, Fc2, s, c, R0, R1, R2);

    // Rt(vl) + cross(-Rt p, Rt va) == Rt(vl + va x p)
    V3 w1 = vl + cross(va, p);
    V3 w2 = al + cross(aa, p);
    V3 nvl{dot(R0, w1), dot(R1, w1), dot(R2, w1)};
    V3 nva{dot(R0, va), dot(R1, va), dot(R2, va)};
    V3 nal{dot(R0, w2), dot(R1, w2), dot(R2, w2)};
    V3 naa{dot(R0, aa), dot(R1, aa), dot(R2, aa)};

    if (AX == 0) {          // jv=(0,0,qd): cross(v,jv)=(v.y*qd,-v.x*qd,0)
        va = {nva.x, nva.y, nva.z + qd};
        aa = {naa.x + va.y * qd, naa.y - va.x * qd, naa.z + qdd};
        vl = nvl;
        al = {nal.x + vl.y * qd, nal.y - vl.x * qd, nal.z};
    } else if (AX == 1) {   // jv=(0,qd,0): cross(v,jv)=(-v.z*qd,0,v.x*qd)
        va = {nva.x, nva.y + qd, nva.z};
        aa = {naa.x - va.z * qd, naa.y + qdd, naa.z + va.x * qd};
        vl = nvl;
        al = {nal.x - vl.z * qd, nal.y, nal.z + vl.x * qd};
    } else {                // jv=(0,-qd,0): cross(v,jv)=(v.z*qd,0,-v.x*qd)
        va = {nva.x, nva.y - qd, nva.z};
        aa = {naa.x + va.z * qd, naa.y - qdd, naa.z - va.x * qd};
        vl = nvl;
        al = {nal.x + vl.z * qd, nal.y, nal.z - vl.x * qd};
    }

    V3 Ial = m * al + cross(aa, mc);
    V3 Iaa = V3{I00 * aa.x + I01 * aa.y + I02 * aa.z,
                I01 * aa.x + I11 * aa.y + I12 * aa.z,
                I02 * aa.x + I12 * aa.y + I22 * aa.z} + cross(mc, al);
    V3 Ivl = m * vl + cross(va, mc);
    V3 Iva = V3{I00 * va.x + I01 * va.y + I02 * va.z,
                I01 * va.x + I11 * va.y + I12 * va.z,
                I02 * va.x + I12 * va.y + I22 * va.z} + cross(mc, vl);
    fl = Ial + cross(va, Ivl);
    fa = Iaa + cross(va, Iva) + cross(vl, Ivl);
}

// bwd: consumes fl/fa by value (from regs pre-barrier, from LDS post-barrier)
template <int AX>
__device__ __forceinline__ float bwd_core(const float4* C4, float s, float c,
                                          V3 fl, V3 fa, V3& cl, V3& ca) {
    const float4 A0 = C4[0], A1 = C4[1], A2 = C4[2];   // only F and p needed
    const V3 Fc0{A0.x, A0.y, A0.z};
    const V3 Fc1{A0.w, A1.x, A1.y};
    const V3 Fc2{A1.z, A1.w, A2.x};
    const V3 p{A2.y, A2.z, A2.w};

    V3 tl = fl + cl;
    V3 ta = fa + ca;
    float tau;
    if (AX == 0) tau = ta.z;
    else if (AX == 1) tau = ta.y;
    else tau = -ta.y;

    V3 R0, R1, R2;
    make_R<AX>(Fc0, Fc1, Fc2, s, c, R0, R1, R2);
    V3 nl = tl.x * R0 + tl.y * R1 + tl.z * R2;   // R @ tl (columns)
    V3 na = ta.x * R0 + ta.y * R1 + ta.z * R2 + cross(p, nl);
    cl = nl;
    ca = na;
    return tau;
}

// ---------- main kernel ----------
// No allocator-forcing attributes: rounds 2/5/7 showed any occupancy cap on
// this kernel triggers catastrophic scratch spill. Pressure management is
// structural: fl/fa[0..4] parked in LDS across a __syncthreads() fence
// (r8: no fence -> promoted back to regs; r9: volatile -> serialized, slow);
// links 5,6 are fwd->bwd fused in registers before the fence.
__global__ __launch_bounds__(BLK) void rnea_main(
    const float* __restrict__ q_g, const float* __restrict__ qd_g,
    const float* __restrict__ qdd_g, const float* __restrict__ cst,
    float* __restrict__ out, int nbatch) {
    __shared__ __align__(16) float sC[CST_TOT];
    __shared__ float sF[BLK * FREC];   // per-thread fl/fa[0..4] records, 33.8 KB
    const int t = threadIdx.x;
    const int row = blockIdx.x * BLK + t;

    if (t < CST_TOT) sC[t] = cst[t];
    __syncthreads();

    const bool ok = row < nbatch;
    const size_t go = (size_t)row * NDOF;
    float qd[NDOF], ss[NDOF], cc[NDOF];
    V3 cl{0.f, 0.f, 0.f}, ca{0.f, 0.f, 0.f};
    float tau5 = 0.f, tau6 = 0.f;
    float* frec = sF + t * FREC;
    const float4* C4 = reinterpret_cast<const float4*>(sC);

    if (ok) {
        float q[NDOF], qdd[NDOF];
#pragma unroll
        for (int d = 0; d < NDOF; d++) q[d] = q_g[go + d];
#pragma unroll
        for (int d = 0; d < NDOF; d++) qd[d] = qd_g[go + d];
#pragma unroll
        for (int d = 0; d < NDOF; d++) qdd[d] = qdd_g[go + d];
        // all transcendentals upfront: independent pairs overlap in the pipe
#pragma unroll
        for (int d = 0; d < NDOF; d++) { ss[d] = __sinf(q[d]); cc[d] = __cosf(q[d]); }

        V3 vl{0.f, 0.f, 0.f}, va{0.f, 0.f, 0.f}, al{0.f, 0.f, 9.81f}, aa{0.f, 0.f, 0.f};
        V3 fl, fa;
        // axis sequence: z, y, z, -y, z, y, z — links 0..4 computed and parked
        fwd_step<0>(C4 + 0 * 6, ss[0], cc[0], qd[0], qdd[0], vl, va, al, aa, fl, fa);
        frec[0] = fl.x; frec[1] = fl.y; frec[2] = fl.z; frec[3] = fa.x; frec[4] = fa.y; frec[5] = fa.z;
        fwd_step<1>(C4 + 1 * 6, ss[1], cc[1], qd[1], qdd[1], vl, va, al, aa, fl, fa);
        frec[6] = fl.x; frec[7] = fl.y; frec[8] = fl.z; frec[9] = fa.x; frec[10] = fa.y; frec[11] = fa.z;
        fwd_step<0>(C4 + 2 * 6, ss[2], cc[2], qd[2], qdd[2], vl, va, al, aa, fl, fa);
        frec[12] = fl.x; frec[13] = fl.y; frec[14] = fl.z; frec[15] = fa.x; frec[16] = fa.y; frec[17] = fa.z;
        fwd_step<2>(C4 + 3 * 6, ss[3], cc[3], qd[3], qdd[3], vl, va, al, aa, fl, fa);
        frec[18] = fl.x; frec[19] = fl.y; frec[20] = fl.z; frec[21] = fa.x; frec[22] = fa.y; frec[23] = fa.z;
        fwd_step<0>(C4 + 4 * 6, ss[4], cc[4], qd[4], qdd[4], vl, va, al, aa, fl, fa);
        frec[24] = fl.x; frec[25] = fl.y; frec[26] = fl.z; frec[27] = fa.x; frec[28] = fa.y; frec[29] = fa.z;

        // links 5,6: fwd -> immediate bwd in registers (never parked)
        V3 fl5, fa5, fl6, fa6;
        fwd_step<1>(C4 + 5 * 6, ss[5], cc[5], qd[5], qdd[5], vl, va, al, aa, fl5, fa5);
        fwd_step<0>(C4 + 6 * 6, ss[6], cc[6], qd[6], qdd[6], vl, va, al, aa, fl6, fa6);
        tau6 = bwd_core<0>(C4 + 6 * 6, ss[6], cc[6], fl6, fa6, cl, ca);
        tau5 = bwd_core<1>(C4 + 5 * 6, ss[5], cc[5], fl5, fa5, cl, ca);
    }

    // LDS fence: blocks store->load forwarding / promotion of sF — ends the
    // fl/fa[0..4] register live ranges at the fwd stores.
    __syncthreads();

    if (ok) {
        float tau[NDOF];
        tau[6] = tau6;
        tau[5] = tau5;
        V3 fl, fa;
        fl = {frec[24], frec[25], frec[26]}; fa = {frec[27], frec[28], frec[29]};
        tau[4] = bwd_core<0>(C4 + 4 * 6, ss[4], cc[4], fl, fa, cl, ca);
        fl = {frec[18], frec[19], frec[20]}; fa = {frec[21], frec[22], frec[23]};
        tau[3] = bwd_core<2>(C4 + 3 * 6, ss[3], cc[3], fl, fa, cl, ca);
        fl = {frec[12], frec[13], frec[14]}; fa = {frec[15], frec[16], frec[17]};
        tau[2] = bwd_core<0>(C4 + 2 * 6, ss[2], cc[2], fl, fa, cl, ca);
        fl = {frec[6], frec[7], frec[8]}; fa = {frec[9], frec[10], frec[11]};
        tau[1] = bwd_core<1>(C4 + 1 * 6, ss[1], cc[1], fl, fa, cl, ca);
        fl = {frec[0], frec[1], frec[2]}; fa = {frec[3], frec[4], frec[5]};
        tau[0] = bwd_core<0>(C4 + 0 * 6, ss[0], cc[0], fl, fa, cl, ca);

#pragma unroll
        for (int d = 0; d < NDOF; d++)
            out[go + d] = tau[d] + sC[d * CST_STRIDE + 22] * qd[d];
    }
}

extern "C" void kernel_launch(void* const* d_in, const int* in_sizes, int n_in,
                              void* d_out, int out_size, void* d_ws, size_t ws_size,
                              hipStream_t stream) {
    const float* q = (const float*)d_in[0];
    const float* qd = (const float*)d_in[1];
    const float* qdd = (const float*)d_in[2];
    const float* rot_fix = (const float*)d_in[3];
    const float* trans_fix = (const float*)d_in[4];
    // d_in[5] = joint_axes: compile-time constant in the reference (z,y,z,-y,z,y,z)
    const float* mass = (const float*)d_in[6];
    const float* com = (const float*)d_in[7];
    const float* inertia = (const float*)d_in[8];
    const float* damping = (const float*)d_in[9];
    float* out = (float*)d_out;
    float* cst = (float*)d_ws;  // 7*24*4 = 672 B

    const int n_elem = in_sizes[0];  // B * 7
    const int B = n_elem / NDOF;
    const int grid = (B + BLK - 1) / BLK;

    rnea_prep<<<1, 64, 0, stream>>>(rot_fix, trans_fix, mass, com, inertia, damping, cst);
    rnea_main<<<grid, BLK, 0, stream>>>(q, qd, qdd, cst, out, B);
}